// Round 1
// baseline (965.057 us; speedup 1.0000x reference)
//
#include <hip/hip_runtime.h>
#include <cmath>

// ---------------- problem constants ----------------
constexpr int BATCH = 4096;
constexpr int DETER = 2048;
constexpr int HID   = 256;
constexpr int STO   = 512;   // SC*SD
constexpr int ACTD  = 17;
constexpr int EMB   = 1024;
constexpr int NG    = 8;     // BLOCKS
constexpr float EPSN = 1e-4f;

// d_out layout (floats): [new_stoch | new_deter | logit]
constexpr int OFF_STOCH = 0;
constexpr int OFF_DETER = BATCH * STO;                 // 2097152
constexpr int OFF_LOGIT = OFF_DETER + BATCH * DETER;   // 10485760

// ws layout (floats)
constexpr int WS_WTH = 0;                              // 8*1024*256
constexpr int WS_WTG = WS_WTH + NG * 1024 * 256;       // 8*256*768
constexpr int WS_X   = WS_WTG + NG * 256 * 768;        // 4096*768
constexpr int WS_XH  = WS_X + BATCH * 768;             // 4096*2048
constexpr int WS_H   = WS_XH + BATCH * DETER;          // 4096*256

#define DINLINE __device__ __forceinline__

DINLINE float sigm(float x)  { return 1.0f / (1.0f + expf(-x)); }
DINLINE float siluf(float x) { return x / (1.0f + expf(-x)); }

// ---------------- shared GEMM building blocks ----------------
// Thread model: THREADS = NW*64, lane tx = tid&63, wave wv = tid>>6.
// Wave wv owns rows [wv*TM, wv*TM+TM). Lane owns cols {tx*4 + s*256, s<TN4}.
// BN = 256*TN4. A_s[BM][KC], W_s[KC][BN].

template<int KC, int BN, int THREADS>
DINLINE void stage_w(const float* __restrict__ Wg, float* __restrict__ W_s,
                     int k0, int K, int tid) {
#pragma unroll
  for (int q = 0; q < (KC * BN / 4) / THREADS; ++q) {
    int e4 = q * THREADS + tid;
    int r = e4 / (BN / 4), c4 = e4 % (BN / 4);
    int k = k0 + r;
    float4 v = make_float4(0.f, 0.f, 0.f, 0.f);
    if (k < K) v = *reinterpret_cast<const float4*>(Wg + (size_t)k * BN + c4 * 4);
    *reinterpret_cast<float4*>(W_s + r * BN + c4 * 4) = v;
  }
}

template<int TM, int TN4, int KC, int BN>
DINLINE void mm_chunk(const float* __restrict__ A_s, const float* __restrict__ W_s,
                      float (&acc)[TM][TN4][4], int tx, int wv) {
#pragma unroll
  for (int kk4 = 0; kk4 < KC / 4; ++kk4) {
    float4 a[TM];
#pragma unroll
    for (int i = 0; i < TM; ++i)
      a[i] = *reinterpret_cast<const float4*>(A_s + (wv * TM + i) * KC + kk4 * 4);
#pragma unroll
    for (int j = 0; j < 4; ++j) {
      float4 w[TN4];
#pragma unroll
      for (int s = 0; s < TN4; ++s)
        w[s] = *reinterpret_cast<const float4*>(W_s + (kk4 * 4 + j) * BN + s * 256 + tx * 4);
#pragma unroll
      for (int i = 0; i < TM; ++i) {
        float av = (j == 0) ? a[i].x : (j == 1) ? a[i].y : (j == 2) ? a[i].z : a[i].w;
#pragma unroll
        for (int s = 0; s < TN4; ++s) {
          acc[i][s][0] = fmaf(av, w[s].x, acc[i][s][0]);
          acc[i][s][1] = fmaf(av, w[s].y, acc[i][s][1]);
          acc[i][s][2] = fmaf(av, w[s].z, acc[i][s][2]);
          acc[i][s][3] = fmaf(av, w[s].w, acc[i][s][3]);
        }
      }
    }
  }
}

// ---------------- kernel 1: weight transpose ----------------
// hid0_k (256,1024,8) -> wTh[g][i(1024)][o(256)] ; gru_k (768,256,8) -> wTg[g][i(256)][o(768)]
__global__ __launch_bounds__(256) void k_transpose(
    const float* __restrict__ hk, const float* __restrict__ gk,
    float* __restrict__ wTh, float* __restrict__ wTg) {
  int t = blockIdx.x * 256 + threadIdx.x;
  constexpr int NH4 = NG * 1024 * 256 / 4;  // 524288
  if (t < NH4) {
    int o4 = t & 63;
    int i  = (t >> 6) & 1023;
    int g  = t >> 16;
    float4 v;
    v.x = hk[((o4 * 4 + 0) * 1024 + i) * 8 + g];
    v.y = hk[((o4 * 4 + 1) * 1024 + i) * 8 + g];
    v.z = hk[((o4 * 4 + 2) * 1024 + i) * 8 + g];
    v.w = hk[((o4 * 4 + 3) * 1024 + i) * 8 + g];
    *reinterpret_cast<float4*>(wTh + (g * 1024 + i) * 256 + o4 * 4) = v;
  } else {
    int e = t - NH4;
    int o4 = e % 192;
    int i  = (e / 192) & 255;
    int g  = e / (192 * 256);
    float4 v;
    v.x = gk[((o4 * 4 + 0) * 256 + i) * 8 + g];
    v.y = gk[((o4 * 4 + 1) * 256 + i) * 8 + g];
    v.z = gk[((o4 * 4 + 2) * 256 + i) * 8 + g];
    v.w = gk[((o4 * 4 + 3) * 256 + i) * 8 + g];
    *reinterpret_cast<float4*>(wTg + (g * 256 + i) * 768 + o4 * 4) = v;
  }
}

// ---------------- kernel 2: input projections x0|x1|x2 -> x (B,768) ----------------
__global__ __launch_bounds__(256) void k_input_proj(
    const float* __restrict__ deter, const float* __restrict__ stoch,
    const float* __restrict__ action,
    const float* __restrict__ w0, const float* __restrict__ b0, const float* __restrict__ s0,
    const float* __restrict__ w1, const float* __restrict__ b1, const float* __restrict__ s1,
    const float* __restrict__ w2, const float* __restrict__ b2, const float* __restrict__ s2,
    float* __restrict__ xout) {
  constexpr int BM = 16, TM = 4, TN4 = 1, KC = 32, BN = 256;
  __shared__ float A_s[BM * KC];
  __shared__ float W_s[KC * BN];
  const int tid = threadIdx.x, tx = tid & 63, wv = tid >> 6;
  const int sec = blockIdx.x >> 8;
  const int m0 = (blockIdx.x & 255) * BM;
  const float* Wp; const float* bp; const float* sp; int K, ocol;
  if (sec == 0)      { Wp = w0; bp = b0; sp = s0; K = 2048; ocol = 0; }
  else if (sec == 1) { Wp = w1; bp = b1; sp = s1; K = 512;  ocol = 256; }
  else               { Wp = w2; bp = b2; sp = s2; K = ACTD; ocol = 512; }

  float acc[TM][TN4][4] = {};
  for (int k0 = 0; k0 < K; k0 += KC) {
#pragma unroll
    for (int q = 0; q < (BM * KC) / 256; ++q) {
      int e = q * 256 + tid;
      int r = e >> 5, c = e & 31;
      int k = k0 + c, b = m0 + r;
      float v = 0.f;
      if (k < K) {
        if (sec == 0)      v = deter[b * 2048 + k];
        else if (sec == 1) v = stoch[b * 512 + k];
        else { float a = action[b * 17 + k]; float m = fabsf(a); v = a / (m > 1.f ? m : 1.f); }
      }
      A_s[r * KC + c] = v;
    }
    stage_w<KC, BN, 256>(Wp, W_s, k0, K, tid);
    __syncthreads();
    mm_chunk<TM, TN4, KC, BN>(A_s, W_s, acc, tx, wv);
    __syncthreads();
  }
  float4 b4 = *reinterpret_cast<const float4*>(bp + tx * 4);
  float4 s4 = *reinterpret_cast<const float4*>(sp + tx * 4);
#pragma unroll
  for (int i = 0; i < TM; ++i) {
    int b = m0 + wv * TM + i;
    float v0 = acc[i][0][0] + b4.x, v1 = acc[i][0][1] + b4.y;
    float v2 = acc[i][0][2] + b4.z, v3 = acc[i][0][3] + b4.w;
    float ss = v0 * v0 + v1 * v1 + v2 * v2 + v3 * v3;
#pragma unroll
    for (int off = 32; off; off >>= 1) ss += __shfl_xor(ss, off);
    float inv = 1.0f / sqrtf(ss * (1.0f / 256.0f) + EPSN);
    float4 o;
    o.x = siluf(v0 * inv * s4.x); o.y = siluf(v1 * inv * s4.y);
    o.z = siluf(v2 * inv * s4.z); o.w = siluf(v3 * inv * s4.w);
    *reinterpret_cast<float4*>(xout + b * 768 + ocol + tx * 4) = o;
  }
}

// ---------------- kernel 3: hid0 block-linear -> yh (B,2048) ----------------
__global__ __launch_bounds__(256) void k_hid0(
    const float* __restrict__ deter, const float* __restrict__ x,
    const float* __restrict__ wTh, const float* __restrict__ hb,
    float* __restrict__ yh) {
  constexpr int BM = 32, TM = 8, TN4 = 1, KC = 32, BN = 256;
  __shared__ float A_s[BM * KC];
  __shared__ float W_s[KC * BN];
  const int tid = threadIdx.x, tx = tid & 63, wv = tid >> 6;
  const int g = blockIdx.x & 7;
  const int m0 = (blockIdx.x >> 3) * BM;
  const float* Wp = wTh + g * (1024 * 256);
  float acc[TM][TN4][4] = {};
  for (int k0 = 0; k0 < 1024; k0 += KC) {
#pragma unroll
    for (int q = 0; q < (BM * KC) / 256; ++q) {
      int e = q * 256 + tid;
      int r = e >> 5, c = e & 31;
      int k = k0 + c, b = m0 + r;
      A_s[r * KC + c] = (k < 256) ? deter[b * 2048 + g * 256 + k] : x[b * 768 + (k - 256)];
    }
    stage_w<KC, BN, 256>(Wp, W_s, k0, 1024, tid);
    __syncthreads();
    mm_chunk<TM, TN4, KC, BN>(A_s, W_s, acc, tx, wv);
    __syncthreads();
  }
  float4 b4 = *reinterpret_cast<const float4*>(hb + g * 256 + tx * 4);
#pragma unroll
  for (int i = 0; i < TM; ++i) {
    int b = m0 + wv * TM + i;
    float4 o;
    o.x = acc[i][0][0] + b4.x; o.y = acc[i][0][1] + b4.y;
    o.z = acc[i][0][2] + b4.z; o.w = acc[i][0][3] + b4.w;
    *reinterpret_cast<float4*>(yh + b * 2048 + g * 256 + tx * 4) = o;
  }
}

// ---------------- kernel 4: in-place rmsnorm(2048)+silu ----------------
__global__ __launch_bounds__(256) void k_rmsnorm2048(
    float* __restrict__ xh, const float* __restrict__ scale) {
  const int b = blockIdx.x, tid = threadIdx.x;
  float* row = xh + b * 2048;
  float4 v0 = *reinterpret_cast<const float4*>(row + tid * 8);
  float4 v1 = *reinterpret_cast<const float4*>(row + tid * 8 + 4);
  float ss = v0.x * v0.x + v0.y * v0.y + v0.z * v0.z + v0.w * v0.w +
             v1.x * v1.x + v1.y * v1.y + v1.z * v1.z + v1.w * v1.w;
#pragma unroll
  for (int off = 32; off; off >>= 1) ss += __shfl_xor(ss, off);
  __shared__ float wsum[4];
  if ((tid & 63) == 0) wsum[tid >> 6] = ss;
  __syncthreads();
  float tot = wsum[0] + wsum[1] + wsum[2] + wsum[3];
  float inv = 1.0f / sqrtf(tot * (1.0f / 2048.0f) + EPSN);
  float4 sc0 = *reinterpret_cast<const float4*>(scale + tid * 8);
  float4 sc1 = *reinterpret_cast<const float4*>(scale + tid * 8 + 4);
  float4 o0, o1;
  o0.x = siluf(v0.x * inv * sc0.x); o0.y = siluf(v0.y * inv * sc0.y);
  o0.z = siluf(v0.z * inv * sc0.z); o0.w = siluf(v0.w * inv * sc0.w);
  o1.x = siluf(v1.x * inv * sc1.x); o1.y = siluf(v1.y * inv * sc1.y);
  o1.z = siluf(v1.z * inv * sc1.z); o1.w = siluf(v1.w * inv * sc1.w);
  *reinterpret_cast<float4*>(row + tid * 8) = o0;
  *reinterpret_cast<float4*>(row + tid * 8 + 4) = o1;
}

// ---------------- kernel 5: gru block-linear + fused GRU -> new_deter ----------------
__global__ __launch_bounds__(512) void k_gru(
    const float* __restrict__ xh, const float* __restrict__ wTg,
    const float* __restrict__ gb, const float* __restrict__ deter,
    float* __restrict__ newdet) {
  constexpr int BM = 32, TM = 4, TN4 = 3, KC = 16, BN = 768;
  __shared__ float A_s[BM * KC];
  __shared__ float W_s[KC * BN];
  const int tid = threadIdx.x, tx = tid & 63, wv = tid >> 6;
  const int g = blockIdx.x & 7;
  const int m0 = (blockIdx.x >> 3) * BM;
  const float* Wp = wTg + g * (256 * 768);
  float acc[TM][TN4][4] = {};
  for (int k0 = 0; k0 < 256; k0 += KC) {
    {
      int r = tid >> 4, c = tid & 15;
      A_s[r * KC + c] = xh[(m0 + r) * 2048 + g * 256 + k0 + c];
    }
    stage_w<KC, BN, 512>(Wp, W_s, k0, 256, tid);
    __syncthreads();
    mm_chunk<TM, TN4, KC, BN>(A_s, W_s, acc, tx, wv);
    __syncthreads();
  }
  const int j0 = tx * 4;
  float4 br = *reinterpret_cast<const float4*>(gb + g * 768 + j0);
  float4 bc = *reinterpret_cast<const float4*>(gb + g * 768 + 256 + j0);
  float4 bu = *reinterpret_cast<const float4*>(gb + g * 768 + 512 + j0);
#pragma unroll
  for (int i = 0; i < TM; ++i) {
    int b = m0 + wv * TM + i;
    float4 d = *reinterpret_cast<const float4*>(deter + b * 2048 + g * 256 + j0);
    float4 o;
    {
      float r = sigm(acc[i][0][0] + br.x);
      float c = acc[i][1][0] + bc.x;
      float u = sigm(acc[i][2][0] + bu.x - 1.0f);
      o.x = u * tanhf(r * c) + (1.0f - u) * d.x;
    }
    {
      float r = sigm(acc[i][0][1] + br.y);
      float c = acc[i][1][1] + bc.y;
      float u = sigm(acc[i][2][1] + bu.y - 1.0f);
      o.y = u * tanhf(r * c) + (1.0f - u) * d.y;
    }
    {
      float r = sigm(acc[i][0][2] + br.z);
      float c = acc[i][1][2] + bc.z;
      float u = sigm(acc[i][2][2] + bu.z - 1.0f);
      o.z = u * tanhf(r * c) + (1.0f - u) * d.z;
    }
    {
      float r = sigm(acc[i][0][3] + br.w);
      float c = acc[i][1][3] + bc.w;
      float u = sigm(acc[i][2][3] + bu.w - 1.0f);
      o.w = u * tanhf(r * c) + (1.0f - u) * d.w;
    }
    *reinterpret_cast<float4*>(newdet + b * 2048 + g * 256 + j0) = o;
  }
}

// ---------------- kernel 6: obs_fc0 on concat(new_deter, embed) ----------------
__global__ __launch_bounds__(256) void k_obs_fc0(
    const float* __restrict__ newdet, const float* __restrict__ embed,
    const float* __restrict__ W, const float* __restrict__ bp,
    const float* __restrict__ sp, float* __restrict__ hout) {
  constexpr int BM = 16, TM = 4, TN4 = 1, KC = 32, BN = 256;
  __shared__ float A_s[BM * KC];
  __shared__ float W_s[KC * BN];
  const int tid = threadIdx.x, tx = tid & 63, wv = tid >> 6;
  const int m0 = blockIdx.x * BM;
  float acc[TM][TN4][4] = {};
  for (int k0 = 0; k0 < 3072; k0 += KC) {
#pragma unroll
    for (int q = 0; q < (BM * KC) / 256; ++q) {
      int e = q * 256 + tid;
      int r = e >> 5, c = e & 31;
      int k = k0 + c, b = m0 + r;
      A_s[r * KC + c] = (k < 2048) ? newdet[b * 2048 + k] : embed[b * 1024 + (k - 2048)];
    }
    stage_w<KC, BN, 256>(W, W_s, k0, 3072, tid);
    __syncthreads();
    mm_chunk<TM, TN4, KC, BN>(A_s, W_s, acc, tx, wv);
    __syncthreads();
  }
  float4 b4 = *reinterpret_cast<const float4*>(bp + tx * 4);
  float4 s4 = *reinterpret_cast<const float4*>(sp + tx * 4);
#pragma unroll
  for (int i = 0; i < TM; ++i) {
    int b = m0 + wv * TM + i;
    float v0 = acc[i][0][0] + b4.x, v1 = acc[i][0][1] + b4.y;
    float v2 = acc[i][0][2] + b4.z, v3 = acc[i][0][3] + b4.w;
    float ss = v0 * v0 + v1 * v1 + v2 * v2 + v3 * v3;
#pragma unroll
    for (int off = 32; off; off >>= 1) ss += __shfl_xor(ss, off);
    float inv = 1.0f / sqrtf(ss * (1.0f / 256.0f) + EPSN);
    float4 o;
    o.x = siluf(v0 * inv * s4.x); o.y = siluf(v1 * inv * s4.y);
    o.z = siluf(v2 * inv * s4.z); o.w = siluf(v3 * inv * s4.w);
    *reinterpret_cast<float4*>(hout + b * 256 + tx * 4) = o;
  }
}

// ---------------- kernel 7: obs_out -> logit + argmax one-hot -> new_stoch ----------------
__global__ __launch_bounds__(256) void k_obs_out(
    const float* __restrict__ h, const float* __restrict__ W,
    const float* __restrict__ ob, float* __restrict__ logit,
    float* __restrict__ stoch_out) {
  constexpr int BM = 16, TM = 4, TN4 = 2, KC = 16, BN = 512;
  __shared__ float A_s[BM * KC];
  __shared__ float W_s[KC * BN];
  const int tid = threadIdx.x, tx = tid & 63, wv = tid >> 6;
  const int m0 = blockIdx.x * BM;
  float acc[TM][TN4][4] = {};
  for (int k0 = 0; k0 < 256; k0 += KC) {
    {
      int r = tid >> 4, c = tid & 15;
      A_s[r * KC + c] = h[(m0 + r) * 256 + k0 + c];
    }
    stage_w<KC, BN, 256>(W, W_s, k0, 256, tid);
    __syncthreads();
    mm_chunk<TM, TN4, KC, BN>(A_s, W_s, acc, tx, wv);
    __syncthreads();
  }
  float4 b0 = *reinterpret_cast<const float4*>(ob + tx * 4);
  float4 b1 = *reinterpret_cast<const float4*>(ob + 256 + tx * 4);
#pragma unroll
  for (int i = 0; i < TM; ++i) {
    int b = m0 + wv * TM + i;
#pragma unroll
    for (int s = 0; s < 2; ++s) {
      float4 bb = s ? b1 : b0;
      float l0 = acc[i][s][0] + bb.x, l1 = acc[i][s][1] + bb.y;
      float l2 = acc[i][s][2] + bb.z, l3 = acc[i][s][3] + bb.w;
      *reinterpret_cast<float4*>(logit + b * 512 + s * 256 + tx * 4) =
          make_float4(l0, l1, l2, l3);
      // exact first-index argmax within each group of 16 (4 lanes x 4 vals)
      int base = s * 256 + tx * 4;
      float bv = l0; int bi = base;
      if (l1 > bv) { bv = l1; bi = base + 1; }
      if (l2 > bv) { bv = l2; bi = base + 2; }
      if (l3 > bv) { bv = l3; bi = base + 3; }
#pragma unroll
      for (int off = 1; off <= 2; off <<= 1) {
        float pv = __shfl_xor(bv, off);
        int   pi = __shfl_xor(bi, off);
        if (pv > bv || (pv == bv && pi < bi)) { bv = pv; bi = pi; }
      }
      float4 oh;
      oh.x = (base + 0 == bi) ? 1.f : 0.f;
      oh.y = (base + 1 == bi) ? 1.f : 0.f;
      oh.z = (base + 2 == bi) ? 1.f : 0.f;
      oh.w = (base + 3 == bi) ? 1.f : 0.f;
      *reinterpret_cast<float4*>(stoch_out + b * 512 + base) = oh;
    }
  }
}

// ---------------- launcher ----------------
extern "C" void kernel_launch(void* const* d_in, const int* in_sizes, int n_in,
                              void* d_out, int out_size, void* d_ws, size_t ws_size,
                              hipStream_t stream) {
  (void)in_sizes; (void)n_in; (void)out_size; (void)ws_size;
  const float* stoch      = (const float*)d_in[0];
  const float* deter      = (const float*)d_in[1];
  const float* action     = (const float*)d_in[2];
  const float* embed      = (const float*)d_in[3];
  const float* in0_w      = (const float*)d_in[4];
  const float* in0_b      = (const float*)d_in[5];
  const float* n0_s       = (const float*)d_in[6];
  const float* in1_w      = (const float*)d_in[7];
  const float* in1_b      = (const float*)d_in[8];
  const float* n1_s       = (const float*)d_in[9];
  const float* in2_w      = (const float*)d_in[10];
  const float* in2_b      = (const float*)d_in[11];
  const float* n2_s       = (const float*)d_in[12];
  const float* hid0_k     = (const float*)d_in[13];
  const float* hid0_b     = (const float*)d_in[14];
  const float* hidn_s     = (const float*)d_in[15];
  const float* gru_k      = (const float*)d_in[16];
  const float* gru_b      = (const float*)d_in[17];
  const float* obs_fc0_w  = (const float*)d_in[18];
  const float* obs_fc0_b  = (const float*)d_in[19];
  const float* obs_n_s    = (const float*)d_in[20];
  const float* obs_out_w  = (const float*)d_in[21];
  const float* obs_out_b  = (const float*)d_in[22];

  float* out = (float*)d_out;
  float* ws  = (float*)d_ws;
  float* wTh = ws + WS_WTH;
  float* wTg = ws + WS_WTG;
  float* xb  = ws + WS_X;
  float* xh  = ws + WS_XH;
  float* hb  = ws + WS_H;

  hipLaunchKernelGGL(k_transpose, dim3(3584), dim3(256), 0, stream,
                     hid0_k, gru_k, wTh, wTg);
  hipLaunchKernelGGL(k_input_proj, dim3(768), dim3(256), 0, stream,
                     deter, stoch, action,
                     in0_w, in0_b, n0_s, in1_w, in1_b, n1_s, in2_w, in2_b, n2_s, xb);
  hipLaunchKernelGGL(k_hid0, dim3(1024), dim3(256), 0, stream,
                     deter, xb, wTh, hid0_b, xh);
  hipLaunchKernelGGL(k_rmsnorm2048, dim3(4096), dim3(256), 0, stream, xh, hidn_s);
  hipLaunchKernelGGL(k_gru, dim3(1024), dim3(512), 0, stream,
                     xh, wTg, gru_b, deter, out + OFF_DETER);
  hipLaunchKernelGGL(k_obs_fc0, dim3(256), dim3(256), 0, stream,
                     out + OFF_DETER, embed, obs_fc0_w, obs_fc0_b, obs_n_s, hb);
  hipLaunchKernelGGL(k_obs_out, dim3(256), dim3(256), 0, stream,
                     hb, obs_out_w, obs_out_b, out + OFF_LOGIT, out + OFF_STOCH);
}

// Round 2
// 698.445 us; speedup vs baseline: 1.3817x; 1.3817x over previous
//
#include <hip/hip_runtime.h>
#include <cmath>

// ---------------- problem constants ----------------
constexpr int BATCH = 4096;
constexpr int DETER = 2048;
constexpr int NG    = 8;
constexpr float EPSN = 1e-4f;

// d_out layout (floats): [new_stoch | new_deter | logit]
constexpr int OFF_STOCH = 0;
constexpr int OFF_DETER = BATCH * 512;
constexpr int OFF_LOGIT = OFF_DETER + BATCH * DETER;

// ws layout (floats)
constexpr size_t WS_WTH = 0;                                // 8*1024*256 = 2097152
constexpr size_t WS_WTG = WS_WTH + (size_t)NG * 1024 * 256; // 8*256*768  = 1572864
constexpr size_t WS_X   = WS_WTG + (size_t)NG * 256 * 768;  // 4096*768
constexpr size_t WS_XH  = WS_X + (size_t)BATCH * 768;       // 4096*2048 (also split-K partial area)
constexpr size_t WS_H   = WS_XH + (size_t)BATCH * DETER;    // 4096*256

#define DINLINE __device__ __forceinline__

DINLINE float sigm(float x)  { return 1.0f / (1.0f + expf(-x)); }
DINLINE float siluf(float x) { return x / (1.0f + expf(-x)); }

// ---------------- shared GEMM building blocks ----------------
// THREADS = NW*64 threads; lane tx = tid&63, wave wv = tid>>6.
// Wave wv owns rows [wv*TM, (wv+1)*TM). Lane owns cols {s*256 + tx*4, s<TN4}.
template<int KC, int BN, int THREADS>
DINLINE void stage_w(const float* __restrict__ Wg, float* __restrict__ W_s,
                     int k0, int K, int tid) {
#pragma unroll
  for (int q = 0; q < (KC * BN / 4) / THREADS; ++q) {
    int e4 = q * THREADS + tid;
    int r = e4 / (BN / 4), c4 = e4 % (BN / 4);
    int k = k0 + r;
    float4 v = make_float4(0.f, 0.f, 0.f, 0.f);
    if (k < K) v = *reinterpret_cast<const float4*>(Wg + (size_t)k * BN + c4 * 4);
    *reinterpret_cast<float4*>(W_s + r * BN + c4 * 4) = v;
  }
}

template<int TM, int TN4, int KC, int BN>
DINLINE void mm_chunk(const float* __restrict__ A_s, const float* __restrict__ W_s,
                      float (&acc)[TM][TN4][4], int tx, int wv) {
#pragma unroll
  for (int kk4 = 0; kk4 < KC / 4; ++kk4) {
    float4 a[TM];
#pragma unroll
    for (int i = 0; i < TM; ++i)
      a[i] = *reinterpret_cast<const float4*>(A_s + (wv * TM + i) * KC + kk4 * 4);
#pragma unroll
    for (int j = 0; j < 4; ++j) {
      float4 w[TN4];
#pragma unroll
      for (int s = 0; s < TN4; ++s)
        w[s] = *reinterpret_cast<const float4*>(W_s + (kk4 * 4 + j) * BN + s * 256 + tx * 4);
#pragma unroll
      for (int i = 0; i < TM; ++i) {
        float av = (j == 0) ? a[i].x : (j == 1) ? a[i].y : (j == 2) ? a[i].z : a[i].w;
#pragma unroll
        for (int s = 0; s < TN4; ++s) {
          acc[i][s][0] = fmaf(av, w[s].x, acc[i][s][0]);
          acc[i][s][1] = fmaf(av, w[s].y, acc[i][s][1]);
          acc[i][s][2] = fmaf(av, w[s].z, acc[i][s][2]);
          acc[i][s][3] = fmaf(av, w[s].w, acc[i][s][3]);
        }
      }
    }
  }
}

// rmsnorm(256)+silu epilogue helper: lane holds 4 values of one row.
DINLINE float4 rms_silu4(float v0, float v1, float v2, float v3, float4 s4) {
  float ss = v0 * v0 + v1 * v1 + v2 * v2 + v3 * v3;
#pragma unroll
  for (int off = 32; off; off >>= 1) ss += __shfl_xor(ss, off);
  float inv = 1.0f / sqrtf(ss * (1.0f / 256.0f) + EPSN);
  float4 o;
  o.x = siluf(v0 * inv * s4.x); o.y = siluf(v1 * inv * s4.y);
  o.z = siluf(v2 * inv * s4.z); o.w = siluf(v3 * inv * s4.w);
  return o;
}

// ---------------- kernel 1: tiled weight transpose ----------------
// hid0_k (o=256, i=1024, g=8) -> wTh[g][i][o];  gru_k (o=768, i=256, g=8) -> wTg[g][i][o]
__global__ __launch_bounds__(256) void k_transpose2(
    const float* __restrict__ hk, const float* __restrict__ gk,
    float* __restrict__ wTh, float* __restrict__ wTg) {
  __shared__ float L[16 * 520];  // [o_l][i_l*8 + g], row stride 520 (pad vs 512)
  const int b = blockIdx.x, t = threadIdx.x;
  const float* src; float* dst; int I, O, o0, i0;
  if (b < 256) { src = hk; dst = wTh; I = 1024; O = 256;
                 int ot = b & 15, it = b >> 4; o0 = ot * 16; i0 = it * 64; }
  else         { src = gk; dst = wTg; I = 256;  O = 768;
                 int b2 = b - 256; int ot = b2 % 48, it = b2 / 48; o0 = ot * 16; i0 = it * 64; }
#pragma unroll
  for (int q = 0; q < 8; ++q) {       // read: contiguous (i,g) runs per o
    int idx = q * 256 + t;
    int o_l = idx >> 7, rem = idx & 127, i_l = rem >> 1, gh = rem & 1;
    float4 v = *reinterpret_cast<const float4*>(
        src + ((size_t)(o0 + o_l) * I + i0 + i_l) * 8 + gh * 4);
    *reinterpret_cast<float4*>(&L[o_l * 520 + i_l * 8 + gh * 4]) = v;
  }
  __syncthreads();
#pragma unroll
  for (int q = 0; q < 8; ++q) {       // write: 64B granules of o per (g,i)
    int idx = q * 256 + t;
    int g = idx >> 8, rem = idx & 255, i_l = rem >> 2, o4 = rem & 3;
    float4 v;
    v.x = L[(o4 * 4 + 0) * 520 + i_l * 8 + g];
    v.y = L[(o4 * 4 + 1) * 520 + i_l * 8 + g];
    v.z = L[(o4 * 4 + 2) * 520 + i_l * 8 + g];
    v.w = L[(o4 * 4 + 3) * 520 + i_l * 8 + g];
    *reinterpret_cast<float4*>(dst + ((size_t)g * I + i0 + i_l) * O + o0 + o4 * 4) = v;
  }
}

// ---------------- kernel 2: input projections ----------------
// grid: [0,256): x0 split-K partials (ks=b&3); [256,320): x1; [320,384): x2
__global__ __launch_bounds__(512) void k_inproj(
    const float* __restrict__ deter, const float* __restrict__ stoch,
    const float* __restrict__ action,
    const float* __restrict__ w0,
    const float* __restrict__ w1, const float* __restrict__ b1, const float* __restrict__ s1,
    const float* __restrict__ w2, const float* __restrict__ b2, const float* __restrict__ s2,
    float* __restrict__ part, float* __restrict__ xb) {
  constexpr int BM = 64, TM = 8, TN4 = 1, KC = 32, BN = 256;
  __shared__ float A_s[BM * KC];
  __shared__ float W_s[KC * BN];
  const int tid = threadIdx.x, tx = tid & 63, wv = tid >> 6;
  const int b = blockIdx.x;
  float acc[TM][TN4][4] = {};
  const int row = tid >> 3, c4 = tid & 7;

  if (b < 256) {
    const int ks = b & 3, mb = b >> 2, m0 = mb * 64, kbase = ks * 512;
    const float* W = w0 + (size_t)kbase * 256;
    for (int k0 = 0; k0 < 512; k0 += KC) {
      *reinterpret_cast<float4*>(A_s + row * KC + c4 * 4) =
          *reinterpret_cast<const float4*>(deter + (size_t)(m0 + row) * 2048 + kbase + k0 + c4 * 4);
      stage_w<KC, BN, 512>(W, W_s, k0, 512, tid);
      __syncthreads();
      mm_chunk<TM, TN4, KC, BN>(A_s, W_s, acc, tx, wv);
      __syncthreads();
    }
#pragma unroll
    for (int i = 0; i < TM; ++i)
      *reinterpret_cast<float4*>(part + ((size_t)ks * BATCH + m0 + wv * TM + i) * 256 + tx * 4) =
          make_float4(acc[i][0][0], acc[i][0][1], acc[i][0][2], acc[i][0][3]);
    return;
  }

  const float* W; const float* bp; const float* sp; int K, ocol;
  int m0;
  if (b < 320) { m0 = (b - 256) * 64; W = w1; bp = b1; sp = s1; K = 512; ocol = 256; }
  else         { m0 = (b - 320) * 64; W = w2; bp = b2; sp = s2; K = 17;  ocol = 512; }

  for (int k0 = 0; k0 < K; k0 += KC) {
    if (K == 512) {
      *reinterpret_cast<float4*>(A_s + row * KC + c4 * 4) =
          *reinterpret_cast<const float4*>(stoch + (size_t)(m0 + row) * 512 + k0 + c4 * 4);
    } else {
      float4 v = make_float4(0.f, 0.f, 0.f, 0.f);
#pragma unroll
      for (int j = 0; j < 4; ++j) {
        int k = c4 * 4 + j;
        if (k < 17) {
          float a = action[(size_t)(m0 + row) * 17 + k];
          float m = fabsf(a);
          (&v.x)[j] = a / (m > 1.f ? m : 1.f);
        }
      }
      *reinterpret_cast<float4*>(A_s + row * KC + c4 * 4) = v;
    }
    stage_w<KC, BN, 512>(W, W_s, k0, K, tid);
    __syncthreads();
    mm_chunk<TM, TN4, KC, BN>(A_s, W_s, acc, tx, wv);
    __syncthreads();
  }
  float4 b4 = *reinterpret_cast<const float4*>(bp + tx * 4);
  float4 s4 = *reinterpret_cast<const float4*>(sp + tx * 4);
#pragma unroll
  for (int i = 0; i < TM; ++i) {
    float4 o = rms_silu4(acc[i][0][0] + b4.x, acc[i][0][1] + b4.y,
                         acc[i][0][2] + b4.z, acc[i][0][3] + b4.w, s4);
    *reinterpret_cast<float4*>(xb + (size_t)(m0 + wv * TM + i) * 768 + ocol + tx * 4) = o;
  }
}

// ---------------- kernel 3: split-K combine + bias + rmsnorm(256) + silu ----------------
__global__ __launch_bounds__(256) void k_combine(
    const float* __restrict__ part, const float* __restrict__ bias,
    const float* __restrict__ scale, float* __restrict__ dst, int dstride) {
  const int tid = threadIdx.x, tx = tid & 63, wv = tid >> 6;
  const size_t row = blockIdx.x * 4 + wv;
  float4 v = make_float4(0.f, 0.f, 0.f, 0.f);
#pragma unroll
  for (int p = 0; p < 4; ++p) {
    float4 t = *reinterpret_cast<const float4*>(part + ((size_t)p * BATCH + row) * 256 + tx * 4);
    v.x += t.x; v.y += t.y; v.z += t.z; v.w += t.w;
  }
  float4 b4 = *reinterpret_cast<const float4*>(bias + tx * 4);
  float4 s4 = *reinterpret_cast<const float4*>(scale + tx * 4);
  float4 o = rms_silu4(v.x + b4.x, v.y + b4.y, v.z + b4.z, v.w + b4.w, s4);
  *reinterpret_cast<float4*>(dst + row * dstride + tx * 4) = o;
}

// ---------------- kernel 4: hid0 block-linear (+bias) -> yh ----------------
__global__ __launch_bounds__(512) void k_hid0(
    const float* __restrict__ deter, const float* __restrict__ x,
    const float* __restrict__ wTh, const float* __restrict__ hb,
    float* __restrict__ yh) {
  constexpr int BM = 64, TM = 8, TN4 = 1, KC = 32, BN = 256;
  __shared__ float A_s[BM * KC];
  __shared__ float W_s[KC * BN];
  const int tid = threadIdx.x, tx = tid & 63, wv = tid >> 6;
  const int g = blockIdx.x & 7, m0 = (blockIdx.x >> 3) * BM;
  const float* W = wTh + (size_t)g * 1024 * 256;
  const int row = tid >> 3, c4 = tid & 7;
  float acc[TM][TN4][4] = {};
  for (int k0 = 0; k0 < 1024; k0 += KC) {
    int k = k0 + c4 * 4;
    float4 v = (k < 256)
        ? *reinterpret_cast<const float4*>(deter + (size_t)(m0 + row) * 2048 + g * 256 + k)
        : *reinterpret_cast<const float4*>(x + (size_t)(m0 + row) * 768 + (k - 256));
    *reinterpret_cast<float4*>(A_s + row * KC + c4 * 4) = v;
    stage_w<KC, BN, 512>(W, W_s, k0, 1024, tid);
    __syncthreads();
    mm_chunk<TM, TN4, KC, BN>(A_s, W_s, acc, tx, wv);
    __syncthreads();
  }
  float4 b4 = *reinterpret_cast<const float4*>(hb + g * 256 + tx * 4);
#pragma unroll
  for (int i = 0; i < TM; ++i)
    *reinterpret_cast<float4*>(yh + (size_t)(m0 + wv * TM + i) * 2048 + g * 256 + tx * 4) =
        make_float4(acc[i][0][0] + b4.x, acc[i][0][1] + b4.y,
                    acc[i][0][2] + b4.z, acc[i][0][3] + b4.w);
}

// ---------------- kernel 5: in-place rmsnorm(2048)+silu ----------------
__global__ __launch_bounds__(256) void k_rmsnorm2048(
    float* __restrict__ xh, const float* __restrict__ scale) {
  const int b = blockIdx.x, tid = threadIdx.x;
  float* row = xh + (size_t)b * 2048;
  float4 v0 = *reinterpret_cast<const float4*>(row + tid * 8);
  float4 v1 = *reinterpret_cast<const float4*>(row + tid * 8 + 4);
  float ss = v0.x * v0.x + v0.y * v0.y + v0.z * v0.z + v0.w * v0.w +
             v1.x * v1.x + v1.y * v1.y + v1.z * v1.z + v1.w * v1.w;
#pragma unroll
  for (int off = 32; off; off >>= 1) ss += __shfl_xor(ss, off);
  __shared__ float wsum[4];
  if ((tid & 63) == 0) wsum[tid >> 6] = ss;
  __syncthreads();
  float tot = wsum[0] + wsum[1] + wsum[2] + wsum[3];
  float inv = 1.0f / sqrtf(tot * (1.0f / 2048.0f) + EPSN);
  float4 sc0 = *reinterpret_cast<const float4*>(scale + tid * 8);
  float4 sc1 = *reinterpret_cast<const float4*>(scale + tid * 8 + 4);
  float4 o0, o1;
  o0.x = siluf(v0.x * inv * sc0.x); o0.y = siluf(v0.y * inv * sc0.y);
  o0.z = siluf(v0.z * inv * sc0.z); o0.w = siluf(v0.w * inv * sc0.w);
  o1.x = siluf(v1.x * inv * sc1.x); o1.y = siluf(v1.y * inv * sc1.y);
  o1.z = siluf(v1.z * inv * sc1.z); o1.w = siluf(v1.w * inv * sc1.w);
  *reinterpret_cast<float4*>(row + tid * 8) = o0;
  *reinterpret_cast<float4*>(row + tid * 8 + 4) = o1;
}

// ---------------- kernel 6: gru block-linear + fused GRU -> new_deter ----------------
__global__ __launch_bounds__(512) void k_gru(
    const float* __restrict__ xh, const float* __restrict__ wTg,
    const float* __restrict__ gb, const float* __restrict__ deter,
    float* __restrict__ newdet) {
  constexpr int BM = 32, TM = 4, TN4 = 3, KC = 16, BN = 768;
  __shared__ float A_s[BM * KC];
  __shared__ float W_s[KC * BN];
  const int tid = threadIdx.x, tx = tid & 63, wv = tid >> 6;
  const int g = blockIdx.x & 7, m0 = (blockIdx.x >> 3) * BM;
  const float* W = wTg + (size_t)g * 256 * 768;
  float acc[TM][TN4][4] = {};
  for (int k0 = 0; k0 < 256; k0 += KC) {
    { int r = tid >> 4, c = tid & 15;
      A_s[r * KC + c] = xh[(size_t)(m0 + r) * 2048 + g * 256 + k0 + c]; }
    stage_w<KC, BN, 512>(W, W_s, k0, 256, tid);
    __syncthreads();
    mm_chunk<TM, TN4, KC, BN>(A_s, W_s, acc, tx, wv);
    __syncthreads();
  }
  const int j0 = tx * 4;
  float4 br = *reinterpret_cast<const float4*>(gb + g * 768 + j0);
  float4 bc = *reinterpret_cast<const float4*>(gb + g * 768 + 256 + j0);
  float4 bu = *reinterpret_cast<const float4*>(gb + g * 768 + 512 + j0);
#pragma unroll
  for (int i = 0; i < TM; ++i) {
    size_t b = m0 + wv * TM + i;
    float4 d = *reinterpret_cast<const float4*>(deter + b * 2048 + g * 256 + j0);
    float4 o;
#pragma unroll
    for (int j = 0; j < 4; ++j) {
      float r = sigm(acc[i][0][j] + (&br.x)[j]);
      float c = acc[i][1][j] + (&bc.x)[j];
      float u = sigm(acc[i][2][j] + (&bu.x)[j] - 1.0f);
      (&o.x)[j] = u * tanhf(r * c) + (1.0f - u) * (&d.x)[j];
    }
    *reinterpret_cast<float4*>(newdet + b * 2048 + g * 256 + j0) = o;
  }
}

// ---------------- kernel 7: obs_fc0 split-K partials ----------------
__global__ __launch_bounds__(512) void k_obsfc0(
    const float* __restrict__ newdet, const float* __restrict__ embed,
    const float* __restrict__ W0, float* __restrict__ part) {
  constexpr int BM = 64, TM = 8, TN4 = 1, KC = 32, BN = 256;
  __shared__ float A_s[BM * KC];
  __shared__ float W_s[KC * BN];
  const int tid = threadIdx.x, tx = tid & 63, wv = tid >> 6;
  const int ks = blockIdx.x & 3, m0 = (blockIdx.x >> 2) * BM;
  const int kbase = ks * 768;
  const float* W = W0 + (size_t)kbase * 256;
  const int row = tid >> 3, c4 = tid & 7;
  float acc[TM][TN4][4] = {};
  for (int k0 = 0; k0 < 768; k0 += KC) {
    int kk = kbase + k0 + c4 * 4;
    float4 v = (kk < 2048)
        ? *reinterpret_cast<const float4*>(newdet + (size_t)(m0 + row) * 2048 + kk)
        : *reinterpret_cast<const float4*>(embed + (size_t)(m0 + row) * 1024 + (kk - 2048));
    *reinterpret_cast<float4*>(A_s + row * KC + c4 * 4) = v;
    stage_w<KC, BN, 512>(W, W_s, k0, 768, tid);
    __syncthreads();
    mm_chunk<TM, TN4, KC, BN>(A_s, W_s, acc, tx, wv);
    __syncthreads();
  }
#pragma unroll
  for (int i = 0; i < TM; ++i)
    *reinterpret_cast<float4*>(part + ((size_t)ks * BATCH + m0 + wv * TM + i) * 256 + tx * 4) =
        make_float4(acc[i][0][0], acc[i][0][1], acc[i][0][2], acc[i][0][3]);
}

// ---------------- kernel 8: obs_out -> logit + argmax one-hot ----------------
__global__ __launch_bounds__(512) void k_obs_out(
    const float* __restrict__ h, const float* __restrict__ W0,
    const float* __restrict__ ob, float* __restrict__ logit,
    float* __restrict__ stoch_out) {
  constexpr int BM = 32, TM = 4, TN4 = 2, KC = 16, BN = 512;
  __shared__ float A_s[BM * KC];
  __shared__ float W_s[KC * BN];
  const int tid = threadIdx.x, tx = tid & 63, wv = tid >> 6;
  const int m0 = blockIdx.x * BM;
  float acc[TM][TN4][4] = {};
  for (int k0 = 0; k0 < 256; k0 += KC) {
    { int r = tid >> 4, c = tid & 15;
      A_s[r * KC + c] = h[(size_t)(m0 + r) * 256 + k0 + c]; }
    stage_w<KC, BN, 512>(W0, W_s, k0, 256, tid);
    __syncthreads();
    mm_chunk<TM, TN4, KC, BN>(A_s, W_s, acc, tx, wv);
    __syncthreads();
  }
  float4 b0 = *reinterpret_cast<const float4*>(ob + tx * 4);
  float4 b1 = *reinterpret_cast<const float4*>(ob + 256 + tx * 4);
#pragma unroll
  for (int i = 0; i < TM; ++i) {
    size_t b = m0 + wv * TM + i;
#pragma unroll
    for (int s = 0; s < 2; ++s) {
      float4 bb = s ? b1 : b0;
      float l0 = acc[i][s][0] + bb.x, l1 = acc[i][s][1] + bb.y;
      float l2 = acc[i][s][2] + bb.z, l3 = acc[i][s][3] + bb.w;
      int base = s * 256 + tx * 4;
      *reinterpret_cast<float4*>(logit + b * 512 + base) = make_float4(l0, l1, l2, l3);
      float bv = l0; int bi = base;
      if (l1 > bv) { bv = l1; bi = base + 1; }
      if (l2 > bv) { bv = l2; bi = base + 2; }
      if (l3 > bv) { bv = l3; bi = base + 3; }
#pragma unroll
      for (int off = 1; off <= 2; off <<= 1) {
        float pv = __shfl_xor(bv, off);
        int   pi = __shfl_xor(bi, off);
        if (pv > bv || (pv == bv && pi < bi)) { bv = pv; bi = pi; }
      }
      float4 oh;
      oh.x = (base + 0 == bi) ? 1.f : 0.f;
      oh.y = (base + 1 == bi) ? 1.f : 0.f;
      oh.z = (base + 2 == bi) ? 1.f : 0.f;
      oh.w = (base + 3 == bi) ? 1.f : 0.f;
      *reinterpret_cast<float4*>(stoch_out + b * 512 + base) = oh;
    }
  }
}

// ---------------- launcher ----------------
extern "C" void kernel_launch(void* const* d_in, const int* in_sizes, int n_in,
                              void* d_out, int out_size, void* d_ws, size_t ws_size,
                              hipStream_t stream) {
  (void)in_sizes; (void)n_in; (void)out_size; (void)ws_size;
  const float* stoch      = (const float*)d_in[0];
  const float* deter      = (const float*)d_in[1];
  const float* action     = (const float*)d_in[2];
  const float* embed      = (const float*)d_in[3];
  const float* in0_w      = (const float*)d_in[4];
  const float* in0_b      = (const float*)d_in[5];
  const float* n0_s       = (const float*)d_in[6];
  const float* in1_w      = (const float*)d_in[7];
  const float* in1_b      = (const float*)d_in[8];
  const float* n1_s       = (const float*)d_in[9];
  const float* in2_w      = (const float*)d_in[10];
  const float* in2_b      = (const float*)d_in[11];
  const float* n2_s       = (const float*)d_in[12];
  const float* hid0_k     = (const float*)d_in[13];
  const float* hid0_b     = (const float*)d_in[14];
  const float* hidn_s     = (const float*)d_in[15];
  const float* gru_k      = (const float*)d_in[16];
  const float* gru_b      = (const float*)d_in[17];
  const float* obs_fc0_w  = (const float*)d_in[18];
  const float* obs_fc0_b  = (const float*)d_in[19];
  const float* obs_n_s    = (const float*)d_in[20];
  const float* obs_out_w  = (const float*)d_in[21];
  const float* obs_out_b  = (const float*)d_in[22];

  float* out = (float*)d_out;
  float* ws  = (float*)d_ws;
  float* wTh  = ws + WS_WTH;
  float* wTg  = ws + WS_WTG;
  float* xb   = ws + WS_X;
  float* xh   = ws + WS_XH;   // doubles as split-K partial area when xh is dead
  float* hb   = ws + WS_H;
  float* part = xh;

  hipLaunchKernelGGL(k_transpose2, dim3(448), dim3(256), 0, stream,
                     hid0_k, gru_k, wTh, wTg);
  hipLaunchKernelGGL(k_inproj, dim3(384), dim3(512), 0, stream,
                     deter, stoch, action, in0_w,
                     in1_w, in1_b, n1_s, in2_w, in2_b, n2_s, part, xb);
  hipLaunchKernelGGL(k_combine, dim3(1024), dim3(256), 0, stream,
                     part, in0_b, n0_s, xb, 768);
  hipLaunchKernelGGL(k_hid0, dim3(512), dim3(512), 0, stream,
                     deter, xb, wTh, hid0_b, xh);
  hipLaunchKernelGGL(k_rmsnorm2048, dim3(4096), dim3(256), 0, stream, xh, hidn_s);
  hipLaunchKernelGGL(k_gru, dim3(1024), dim3(512), 0, stream,
                     xh, wTg, gru_b, deter, out + OFF_DETER);
  hipLaunchKernelGGL(k_obsfc0, dim3(256), dim3(512), 0, stream,
                     out + OFF_DETER, embed, obs_fc0_w, part);
  hipLaunchKernelGGL(k_combine, dim3(1024), dim3(256), 0, stream,
                     part, obs_fc0_b, obs_n_s, hb, 256);
  hipLaunchKernelGGL(k_obs_out, dim3(128), dim3(512), 0, stream,
                     hb, obs_out_w, obs_out_b, out + OFF_LOGIT, out + OFF_STOCH);
}